// Round 13
// baseline (7561.871 us; speedup 1.0000x reference)
//
#include <hip/hip_runtime.h>
#include <hip/hip_bf16.h>
#include <math.h>

// DiffusionFlow: fused 10-step flow + log-det on MI355X.
// Round 13: all 13 prior configs show occupancy = exactly ONE WG/CU (8 waves
// for 512-thr, 16 for 1024-thr) regardless of VGPR/LDS -> the only route to
// 16 waves/CU is the 1024-thr WG (r10/r11, 46% occ). Their 1.9-2.1GB spills
// came from (a) "+a" asm tied-operand copies and (b) full-unroll K-loop load
// hoisting past the 64-arch budget. Fix: intrinsic 32x32x16 MFMA (accs ->
// AGPR naturally, 48<=64 granule) + #pragma unroll 2 K-loop (bounded hoist).
// Geometry: 32 samples/WG, 16 waves, wave owns 32 cols; Xbuf rows h 0-31,
// u0 32-63, u1 64-95; swizzle byteoff ^= (row&7)<<4 on 16B granules.
// L0/L3/epilogue = r11/r12 register-lean versions (<=40 live, verified).

typedef float  f32x4  __attribute__((ext_vector_type(4)));
typedef float  f32x16 __attribute__((ext_vector_type(16)));
typedef __bf16 bf16x8 __attribute__((ext_vector_type(8)));

static __device__ __forceinline__ unsigned pkbf2(float a, float b) {
    unsigned short lo = __builtin_bit_cast(unsigned short, __float2bfloat16(a));
    unsigned short hi = __builtin_bit_cast(unsigned short, __float2bfloat16(b));
    return (unsigned)lo | ((unsigned)hi << 16);
}

// ---- pack W (512x512 row-major fp32) -> bf16 A-frag order for 32x32x16 ----
// out[(((c*16+nb)*64)+l)*8+j] = W[nb*32+(l&31)][c*16+(l>>5)*8+j]  (verified r5-r11)
__global__ void pack_w_kernel(const float* __restrict__ W,
                              __hip_bfloat16* __restrict__ out) {
    int i  = blockIdx.x * 512 + threadIdx.x;
    int c  = i >> 13;
    int nb = (i >> 9) & 15;
    int l  = (i >> 3) & 63;
    int j  = i & 7;
    int n  = nb * 32 + (l & 31);
    int k  = c * 16 + ((l >> 5) << 3) + j;
    out[i] = __float2bfloat16(W[n * 512 + k]);
}

// ---- pack W0 cols 0,1 -> contiguous [512][2] fp32 ----
__global__ void pack_w0_kernel(const float* __restrict__ W0,
                               float* __restrict__ w01) {
    int o = threadIdx.x;
    w01[o * 2 + 0] = W0[o * 34 + 0];
    w01[o * 2 + 1] = W0[o * 34 + 1];
}

// ---- c_step[k][o] = b0[o] + W0[o,2:34] . temb(t_k) ----
__global__ void cstep_kernel(const float* __restrict__ W0,
                             const float* __restrict__ b0,
                             float* __restrict__ cst) {
    int k = blockIdx.x;
    int o = threadIdx.x;
    float t = (float)k * 0.1f;
    float acc = b0[o];
    #pragma unroll
    for (int j = 0; j < 16; ++j) {
        float f   = expf(-9.210340371976184f * (float)j / 16.0f);
        float arg = t * f;
        acc += W0[o * 34 + 2 + j]  * sinf(arg);
        acc += W0[o * 34 + 18 + j] * cosf(arg);
    }
    cst[k * 512 + o] = acc;
}

__global__ __launch_bounds__(1024)
void flow_kernel(const float* __restrict__ x,
                 const float* __restrict__ w01,
                 const float* __restrict__ cst,
                 const __hip_bfloat16* __restrict__ Wpk1,
                 const __hip_bfloat16* __restrict__ Wpk2,
                 const float* __restrict__ b1,
                 const float* __restrict__ b2,
                 const float* __restrict__ W3,
                 const float* __restrict__ b3v,
                 float* __restrict__ out)
{
    __shared__ __align__(16) __hip_bfloat16 Xbuf[96 * 512];  // 96 KB
    __shared__ float zbuf[32][2];
    __shared__ float ldbuf[32];

    const int tid  = threadIdx.x;
    const int lane = tid & 63;
    const int wid  = tid >> 6;        // 0..15 -> cols [wid*32, wid*32+32)
    const int l31  = lane & 31;
    const int hi   = lane >> 5;       // 0/1
    const int n0w  = wid << 5;
    const int wgs  = blockIdx.x << 5; // 32 samples per WG

    if (tid < 32) {
        zbuf[tid][0] = x[(wgs + tid) * 2 + 0];
        zbuf[tid][1] = x[(wgs + tid) * 2 + 1];
        ldbuf[tid]   = 0.0f;
    }

    // B-frag (X from LDS): rows l31 / 32+l31 / 64+l31
    const int rowb0 = l31 << 10;
    const int rowb1 = (32 + l31) << 10;
    const int rowb2 = (64 + l31) << 10;
    const int swzB  = (l31 & 7) << 4;
    const int hi16  = hi << 4;
    // A-frag: uint4 index = c*1024 + abase  (wave wid owns n-block wid)
    const int abase = (wid << 6) + lane;
    const uint4* Wp1 = (const uint4*)Wpk1;
    const uint4* Wp2 = (const uint4*)Wpk2;

    // L0/L3 split: s0 = sample (tid>>5, 0..31), t32 = 32-way column split
    const int s0   = tid >> 5;
    const int t32  = tid & 31;
    const int swz0 = (s0 & 7) << 4;

    __syncthreads();

    #pragma unroll 1
    for (int step = 0; step < 10; ++step) {
        // ---------- layer 0: rank-2 + step-constant, 16 outs/thread ----------
        {
            const float z0 = zbuf[s0][0];
            const float z1 = zbuf[s0][1];
            const float* cs = cst + (step << 9);
            char* base0 = (char*)Xbuf + (s0 << 10);
            #pragma unroll
            for (int m = 0; m < 2; ++m) {
                int ob = (t32 << 4) + (m << 3);    // element base, 8 outs
                const float4* wv4 = (const float4*)(w01 + (ob << 1));
                const float4* cv4 = (const float4*)(cs + ob);
                unsigned ph[4], p0[4], p1[4];
                #pragma unroll
                for (int jj = 0; jj < 4; ++jj) {
                    float4 wv = wv4[jj];                    // pairs (x,y),(z,w)
                    float4 cv = cv4[jj >> 1];
                    float c0 = (jj & 1) ? cv.z : cv.x;
                    float c1 = (jj & 1) ? cv.w : cv.y;
                    float a0  = fmaf(z0, wv.x, fmaf(z1, wv.y, c0));
                    float sg0 = 1.0f / (1.0f + __expf(-a0));
                    float h0  = a0 * sg0;
                    float sp0 = fmaf(h0, 1.0f - sg0, sg0);  // silu'(a0)
                    float a1  = fmaf(z0, wv.z, fmaf(z1, wv.w, c1));
                    float sg1 = 1.0f / (1.0f + __expf(-a1));
                    float h1  = a1 * sg1;
                    float sp1 = fmaf(h1, 1.0f - sg1, sg1);
                    ph[jj] = pkbf2(h0, h1);
                    p0[jj] = pkbf2(sp0 * wv.x, sp1 * wv.z);
                    p1[jj] = pkbf2(sp0 * wv.y, sp1 * wv.w);
                }
                int off = (ob << 1) ^ swz0;
                uint4 vph = {ph[0], ph[1], ph[2], ph[3]};
                uint4 vp0 = {p0[0], p0[1], p0[2], p0[3]};
                uint4 vp1 = {p1[0], p1[1], p1[2], p1[3]};
                *(uint4*)(base0 + off)              = vph;
                *(uint4*)(base0 + (32 << 10) + off) = vp0;
                *(uint4*)(base0 + (64 << 10) + off) = vp1;
            }
        }
        __syncthreads();

        // ---------- layers 1,2: D = W @ X^T via 32x32x16 MFMA (intrinsic) ----------
        #pragma unroll 1
        for (int layer = 0; layer < 2; ++layer) {
            const uint4* __restrict__ Wp   = layer ? Wp2 : Wp1;
            const float* __restrict__ bias = layer ? b2  : b1;

            f32x16 acc0 = (f32x16)(0.0f);   // h stream  (AGPR)
            f32x16 acc1 = (f32x16)(0.0f);   // u0
            f32x16 acc2 = (f32x16)(0.0f);   // u1

            uint4 a[2];                     // A depth-2 prefetch
            a[0] = Wp[abase];
            a[1] = Wp[abase + 1024];

            #pragma unroll 2
            for (int c = 0; c < 32; ++c) {
                uint4 an;
                if (c + 2 < 32) an = Wp[abase + (c + 2) * 1024];
                int kx = ((c << 5) | hi16) ^ swzB;
                bf16x8 bf0 = __builtin_bit_cast(bf16x8, *(const uint4*)((const char*)Xbuf + rowb0 + kx));
                bf16x8 bf1 = __builtin_bit_cast(bf16x8, *(const uint4*)((const char*)Xbuf + rowb1 + kx));
                bf16x8 bf2 = __builtin_bit_cast(bf16x8, *(const uint4*)((const char*)Xbuf + rowb2 + kx));
                bf16x8 av  = __builtin_bit_cast(bf16x8, a[c & 1]);
                __builtin_amdgcn_s_setprio(1);
                acc0 = __builtin_amdgcn_mfma_f32_32x32x16_bf16(av, bf0, acc0, 0, 0, 0);
                acc1 = __builtin_amdgcn_mfma_f32_32x32x16_bf16(av, bf1, acc1, 0, 0, 0);
                acc2 = __builtin_amdgcn_mfma_f32_32x32x16_bf16(av, bf2, acc2, 0, 0, 0);
                __builtin_amdgcn_s_setprio(0);
                if (c + 2 < 32) a[c & 1] = an;
            }

            __syncthreads();   // all waves done reading Xbuf before overwrite

            // epilogue: silu + JVP coupling; D col = sample = l31,
            // D row n = n0w + (reg&3) + 8*(reg>>2) + 4*hi  (m74 layout, verified)
            {
                char* pb = (char*)Xbuf + (l31 << 10);
                #pragma unroll
                for (int q = 0; q < 4; ++q) {
                    int nq = n0w + 8 * q + 4 * hi;          // 4 consecutive n
                    f32x4 bq = *(const f32x4*)(bias + nq);
                    float hv[4], u0v[4], u1v[4];
                    #pragma unroll
                    for (int k = 0; k < 4; ++k) {
                        int reg = 4 * q + k;
                        float aa  = acc0[reg] + bq[k];
                        float sig = 1.0f / (1.0f + __expf(-aa));
                        float h   = aa * sig;
                        float sp  = fmaf(h, 1.0f - sig, sig);
                        hv[k]  = h;
                        u0v[k] = sp * acc1[reg];
                        u1v[k] = sp * acc2[reg];
                    }
                    int off = (nq << 1) ^ swzB;
                    uint2 vh = {pkbf2(hv[0],  hv[1]),  pkbf2(hv[2],  hv[3])};
                    uint2 v0 = {pkbf2(u0v[0], u0v[1]), pkbf2(u0v[2], u0v[3])};
                    uint2 v1 = {pkbf2(u1v[0], u1v[1]), pkbf2(u1v[2], u1v[3])};
                    *(uint2*)(pb + off)              = vh;
                    *(uint2*)(pb + (32 << 10) + off) = v0;
                    *(uint2*)(pb + (64 << 10) + off) = v1;
                }
            }
            __syncthreads();
        }

        // ---------- layer 3: six length-512 dots, two 8-elem passes ----------
        {
            float d0 = 0.f, d1 = 0.f, d2 = 0.f, d3 = 0.f, d4 = 0.f, d5 = 0.f;
            #pragma unroll
            for (int p = 0; p < 2; ++p) {
                int eb = (t32 << 4) + (p << 3);    // element base, 8 elems
                const float4* wr0 = (const float4*)(W3 + eb);
                const float4* wr1 = (const float4*)(W3 + 512 + eb);
                float4 wa0 = wr0[0], wa1 = wr0[1];
                float4 wb0 = wr1[0], wb1 = wr1[1];
                #pragma unroll
                for (int st = 0; st < 3; ++st) {
                    int row = s0 + st * 32;
                    int off = (row << 10) + ((((t32 << 5) + (p << 4))) ^ swz0);
                    uint4 v = *(const uint4*)((const char*)Xbuf + off);
                    float e0 = __uint_as_float(v.x << 16);
                    float e1 = __uint_as_float(v.x & 0xffff0000u);
                    float e2 = __uint_as_float(v.y << 16);
                    float e3 = __uint_as_float(v.y & 0xffff0000u);
                    float e4 = __uint_as_float(v.z << 16);
                    float e5 = __uint_as_float(v.z & 0xffff0000u);
                    float e6 = __uint_as_float(v.w << 16);
                    float e7 = __uint_as_float(v.w & 0xffff0000u);
                    float sa = wa0.x * e0;
                    sa = fmaf(wa0.y, e1, sa); sa = fmaf(wa0.z, e2, sa);
                    sa = fmaf(wa0.w, e3, sa); sa = fmaf(wa1.x, e4, sa);
                    sa = fmaf(wa1.y, e5, sa); sa = fmaf(wa1.z, e6, sa);
                    sa = fmaf(wa1.w, e7, sa);
                    float sb = wb0.x * e0;
                    sb = fmaf(wb0.y, e1, sb); sb = fmaf(wb0.z, e2, sb);
                    sb = fmaf(wb0.w, e3, sb); sb = fmaf(wb1.x, e4, sb);
                    sb = fmaf(wb1.y, e5, sb); sb = fmaf(wb1.z, e6, sb);
                    sb = fmaf(wb1.w, e7, sb);
                    if      (st == 0) { d0 += sa; d1 += sb; }
                    else if (st == 1) { d2 += sa; d3 += sb; }
                    else              { d4 += sa; d5 += sb; }
                }
            }
            #pragma unroll
            for (int m = 1; m < 32; m <<= 1) {
                d0 += __shfl_xor(d0, m);
                d1 += __shfl_xor(d1, m);
                d2 += __shfl_xor(d2, m);
                d3 += __shfl_xor(d3, m);
                d4 += __shfl_xor(d4, m);
                d5 += __shfl_xor(d5, m);
            }
            if (t32 == 0) {
                float v0 = d0 + b3v[0];
                float v1 = d1 + b3v[1];
                float det = (1.0f + 0.1f * d2) * (1.0f + 0.1f * d5)
                          - 0.01f * d4 * d3;
                ldbuf[s0] += logf(fmaxf(fabsf(det), 1e-8f));
                zbuf[s0][0] += 0.1f * v0;
                zbuf[s0][1] += 0.1f * v1;
            }
        }
        __syncthreads();
    }

    if (tid < 32) {
        float z0 = zbuf[tid][0], z1 = zbuf[tid][1];
        out[wgs + tid] = -0.5f * (z0 * z0 + z1 * z1) - 1.8378770664093453f + ldbuf[tid];
    }
}

extern "C" void kernel_launch(void* const* d_in, const int* in_sizes, int n_in,
                              void* d_out, int out_size, void* d_ws, size_t ws_size,
                              hipStream_t stream) {
    const float* x  = (const float*)d_in[0];
    const float* W0 = (const float*)d_in[1];   // (512, 34)
    const float* b0 = (const float*)d_in[2];
    const float* W1 = (const float*)d_in[3];   // (512, 512)
    const float* b1 = (const float*)d_in[4];
    const float* W2 = (const float*)d_in[5];
    const float* b2 = (const float*)d_in[6];
    const float* W3 = (const float*)d_in[7];   // (2, 512)
    const float* b3 = (const float*)d_in[8];
    float* out = (float*)d_out;

    char* ws = (char*)d_ws;
    __hip_bfloat16* wpk1 = (__hip_bfloat16*)ws;                  // 512 KB
    __hip_bfloat16* wpk2 = (__hip_bfloat16*)(ws + (512u << 10)); // 512 KB
    float*          cstp = (float*)(ws + (1024u << 10));         // 20 KB
    float*          w01p = (float*)(ws + (1044u << 10));         // 4 KB

    pack_w_kernel<<<512, 512, 0, stream>>>(W1, wpk1);
    pack_w_kernel<<<512, 512, 0, stream>>>(W2, wpk2);
    cstep_kernel<<<10, 512, 0, stream>>>(W0, b0, cstp);
    pack_w0_kernel<<<1, 512, 0, stream>>>(W0, w01p);
    flow_kernel<<<131072 / 32, 1024, 0, stream>>>(x, w01p, cstp, wpk1, wpk2,
                                                  b1, b2, W3, b3, out);
}

// Round 14
// 6741.202 us; speedup vs baseline: 1.1217x; 1.1217x over previous
//
#include <hip/hip_runtime.h>
#include <hip/hip_bf16.h>
#include <math.h>

// DiffusionFlow: fused 10-step flow + log-det on MI355X.
// Round 14 = r13 geometry (32 samples/WG, 1024 thr / 16 waves, wave owns 32
// cols, 32x32x16 intrinsic MFMA -> acc in AGPR) with the K-loop rewritten as
// a ROLLED (#pragma unroll 1), guard-free, manually double-buffered loop:
// two named A/B register sets ping-pong over a 2-c body (15 iters + peeled
// tail). In-loop arch live ~44 <= 64 budget -> should finally kill the
// 1.3-2.1GB scratch spills that poisoned every 1024-thr round (r10/r11/r13).
// K-loop is L2-BW-bound (512KB W per layer per WG @ ~56B/cyc/CU = 9.1k cyc);
// floor ~1.2ms L2 + ~0.5ms serial = 1.8-2.5ms.
// Xbuf rows: h 0-31, u0 32-63, u1 64-95; swizzle byteoff ^= (row&7)<<4.

typedef float  f32x4  __attribute__((ext_vector_type(4)));
typedef float  f32x16 __attribute__((ext_vector_type(16)));
typedef __bf16 bf16x8 __attribute__((ext_vector_type(8)));

static __device__ __forceinline__ unsigned pkbf2(float a, float b) {
    unsigned short lo = __builtin_bit_cast(unsigned short, __float2bfloat16(a));
    unsigned short hi = __builtin_bit_cast(unsigned short, __float2bfloat16(b));
    return (unsigned)lo | ((unsigned)hi << 16);
}

// ---- pack W (512x512 row-major fp32) -> bf16 A-frag order for 32x32x16 ----
// out[(((c*16+nb)*64)+l)*8+j] = W[nb*32+(l&31)][c*16+(l>>5)*8+j]  (verified r5-r13)
__global__ void pack_w_kernel(const float* __restrict__ W,
                              __hip_bfloat16* __restrict__ out) {
    int i  = blockIdx.x * 512 + threadIdx.x;
    int c  = i >> 13;
    int nb = (i >> 9) & 15;
    int l  = (i >> 3) & 63;
    int j  = i & 7;
    int n  = nb * 32 + (l & 31);
    int k  = c * 16 + ((l >> 5) << 3) + j;
    out[i] = __float2bfloat16(W[n * 512 + k]);
}

// ---- pack W0 cols 0,1 -> contiguous [512][2] fp32 ----
__global__ void pack_w0_kernel(const float* __restrict__ W0,
                               float* __restrict__ w01) {
    int o = threadIdx.x;
    w01[o * 2 + 0] = W0[o * 34 + 0];
    w01[o * 2 + 1] = W0[o * 34 + 1];
}

// ---- c_step[k][o] = b0[o] + W0[o,2:34] . temb(t_k) ----
__global__ void cstep_kernel(const float* __restrict__ W0,
                             const float* __restrict__ b0,
                             float* __restrict__ cst) {
    int k = blockIdx.x;
    int o = threadIdx.x;
    float t = (float)k * 0.1f;
    float acc = b0[o];
    #pragma unroll
    for (int j = 0; j < 16; ++j) {
        float f   = expf(-9.210340371976184f * (float)j / 16.0f);
        float arg = t * f;
        acc += W0[o * 34 + 2 + j]  * sinf(arg);
        acc += W0[o * 34 + 18 + j] * cosf(arg);
    }
    cst[k * 512 + o] = acc;
}

__global__ __launch_bounds__(1024)
void flow_kernel(const float* __restrict__ x,
                 const float* __restrict__ w01,
                 const float* __restrict__ cst,
                 const __hip_bfloat16* __restrict__ Wpk1,
                 const __hip_bfloat16* __restrict__ Wpk2,
                 const float* __restrict__ b1,
                 const float* __restrict__ b2,
                 const float* __restrict__ W3,
                 const float* __restrict__ b3v,
                 float* __restrict__ out)
{
    __shared__ __align__(16) __hip_bfloat16 Xbuf[96 * 512];  // 96 KB
    __shared__ float zbuf[32][2];
    __shared__ float ldbuf[32];

    const int tid  = threadIdx.x;
    const int lane = tid & 63;
    const int wid  = tid >> 6;        // 0..15 -> cols [wid*32, wid*32+32)
    const int l31  = lane & 31;
    const int hi   = lane >> 5;       // 0/1
    const int n0w  = wid << 5;
    const int wgs  = blockIdx.x << 5; // 32 samples per WG

    if (tid < 32) {
        zbuf[tid][0] = x[(wgs + tid) * 2 + 0];
        zbuf[tid][1] = x[(wgs + tid) * 2 + 1];
        ldbuf[tid]   = 0.0f;
    }

    // B-frag (X from LDS): rows l31 / 32+l31 / 64+l31
    const int rowb0 = l31 << 10;
    const int rowb1 = (32 + l31) << 10;
    const int rowb2 = (64 + l31) << 10;
    const int swzB  = (l31 & 7) << 4;
    const int hi16  = hi << 4;
    // A-frag: uint4 index = c*1024 + abase  (wave wid owns n-block wid)
    const int abase = (wid << 6) + lane;
    const uint4* Wp1 = (const uint4*)Wpk1;
    const uint4* Wp2 = (const uint4*)Wpk2;

    // L0/L3 split: s0 = sample (tid>>5, 0..31), t32 = 32-way column split
    const int s0   = tid >> 5;
    const int t32  = tid & 31;
    const int swz0 = (s0 & 7) << 4;

    const char* xb = (const char*)Xbuf;

    __syncthreads();

    #pragma unroll 1
    for (int step = 0; step < 10; ++step) {
        // ---------- layer 0: rank-2 + step-constant, 16 outs/thread ----------
        {
            const float z0 = zbuf[s0][0];
            const float z1 = zbuf[s0][1];
            const float* cs = cst + (step << 9);
            char* base0 = (char*)Xbuf + (s0 << 10);
            #pragma unroll
            for (int m = 0; m < 2; ++m) {
                int ob = (t32 << 4) + (m << 3);    // element base, 8 outs
                const float4* wv4 = (const float4*)(w01 + (ob << 1));
                const float4* cv4 = (const float4*)(cs + ob);
                unsigned ph[4], p0[4], p1[4];
                #pragma unroll
                for (int jj = 0; jj < 4; ++jj) {
                    float4 wv = wv4[jj];                    // pairs (x,y),(z,w)
                    float4 cv = cv4[jj >> 1];
                    float c0 = (jj & 1) ? cv.z : cv.x;
                    float c1 = (jj & 1) ? cv.w : cv.y;
                    float a0  = fmaf(z0, wv.x, fmaf(z1, wv.y, c0));
                    float sg0 = 1.0f / (1.0f + __expf(-a0));
                    float h0  = a0 * sg0;
                    float sp0 = fmaf(h0, 1.0f - sg0, sg0);  // silu'(a0)
                    float a1  = fmaf(z0, wv.z, fmaf(z1, wv.w, c1));
                    float sg1 = 1.0f / (1.0f + __expf(-a1));
                    float h1  = a1 * sg1;
                    float sp1 = fmaf(h1, 1.0f - sg1, sg1);
                    ph[jj] = pkbf2(h0, h1);
                    p0[jj] = pkbf2(sp0 * wv.x, sp1 * wv.z);
                    p1[jj] = pkbf2(sp0 * wv.y, sp1 * wv.w);
                }
                int off = (ob << 1) ^ swz0;
                uint4 vph = {ph[0], ph[1], ph[2], ph[3]};
                uint4 vp0 = {p0[0], p0[1], p0[2], p0[3]};
                uint4 vp1 = {p1[0], p1[1], p1[2], p1[3]};
                *(uint4*)(base0 + off)              = vph;
                *(uint4*)(base0 + (32 << 10) + off) = vp0;
                *(uint4*)(base0 + (64 << 10) + off) = vp1;
            }
        }
        __syncthreads();

        // ---------- layers 1,2: D = W @ X^T via 32x32x16 MFMA (intrinsic) ----------
        #pragma unroll 1
        for (int layer = 0; layer < 2; ++layer) {
            const uint4* __restrict__ Wp   = layer ? Wp2 : Wp1;
            const float* __restrict__ bias = layer ? b2  : b1;

            f32x16 acc0 = (f32x16)(0.0f);   // h stream  (AGPR)
            f32x16 acc1 = (f32x16)(0.0f);   // u0
            f32x16 acc2 = (f32x16)(0.0f);   // u1

            // ---- set A = k-chunk 0 ----
            uint4  aA = Wp[abase];
            int    kA = hi16 ^ swzB;
            bf16x8 bA0 = __builtin_bit_cast(bf16x8, *(const uint4*)(xb + rowb0 + kA));
            bf16x8 bA1 = __builtin_bit_cast(bf16x8, *(const uint4*)(xb + rowb1 + kA));
            bf16x8 bA2 = __builtin_bit_cast(bf16x8, *(const uint4*)(xb + rowb2 + kA));

            // rolled, guard-free, 2 chunks per body; 15 iters covering c=0..29
            #pragma unroll 1
            for (int c = 0; c < 30; c += 2) {
                // prefetch set B = c+1
                uint4  aB = Wp[abase + (c + 1) * 1024];
                int    kB = (((c + 1) << 5) | hi16) ^ swzB;
                bf16x8 bB0 = __builtin_bit_cast(bf16x8, *(const uint4*)(xb + rowb0 + kB));
                bf16x8 bB1 = __builtin_bit_cast(bf16x8, *(const uint4*)(xb + rowb1 + kB));
                bf16x8 bB2 = __builtin_bit_cast(bf16x8, *(const uint4*)(xb + rowb2 + kB));
                // compute set A (chunk c)
                {
                    bf16x8 av = __builtin_bit_cast(bf16x8, aA);
                    __builtin_amdgcn_s_setprio(1);
                    acc0 = __builtin_amdgcn_mfma_f32_32x32x16_bf16(av, bA0, acc0, 0, 0, 0);
                    acc1 = __builtin_amdgcn_mfma_f32_32x32x16_bf16(av, bA1, acc1, 0, 0, 0);
                    acc2 = __builtin_amdgcn_mfma_f32_32x32x16_bf16(av, bA2, acc2, 0, 0, 0);
                    __builtin_amdgcn_s_setprio(0);
                }
                // prefetch set A = c+2
                aA = Wp[abase + (c + 2) * 1024];
                int kA2 = (((c + 2) << 5) | hi16) ^ swzB;
                bA0 = __builtin_bit_cast(bf16x8, *(const uint4*)(xb + rowb0 + kA2));
                bA1 = __builtin_bit_cast(bf16x8, *(const uint4*)(xb + rowb1 + kA2));
                bA2 = __builtin_bit_cast(bf16x8, *(const uint4*)(xb + rowb2 + kA2));
                // compute set B (chunk c+1)
                {
                    bf16x8 av = __builtin_bit_cast(bf16x8, aB);
                    __builtin_amdgcn_s_setprio(1);
                    acc0 = __builtin_amdgcn_mfma_f32_32x32x16_bf16(av, bB0, acc0, 0, 0, 0);
                    acc1 = __builtin_amdgcn_mfma_f32_32x32x16_bf16(av, bB1, acc1, 0, 0, 0);
                    acc2 = __builtin_amdgcn_mfma_f32_32x32x16_bf16(av, bB2, acc2, 0, 0, 0);
                    __builtin_amdgcn_s_setprio(0);
                }
            }
            // tail: chunk 30 is in set A; prefetch 31 then compute both
            {
                uint4  aB = Wp[abase + 31 * 1024];
                int    kB = ((31 << 5) | hi16) ^ swzB;
                bf16x8 bB0 = __builtin_bit_cast(bf16x8, *(const uint4*)(xb + rowb0 + kB));
                bf16x8 bB1 = __builtin_bit_cast(bf16x8, *(const uint4*)(xb + rowb1 + kB));
                bf16x8 bB2 = __builtin_bit_cast(bf16x8, *(const uint4*)(xb + rowb2 + kB));
                bf16x8 av = __builtin_bit_cast(bf16x8, aA);
                acc0 = __builtin_amdgcn_mfma_f32_32x32x16_bf16(av, bA0, acc0, 0, 0, 0);
                acc1 = __builtin_amdgcn_mfma_f32_32x32x16_bf16(av, bA1, acc1, 0, 0, 0);
                acc2 = __builtin_amdgcn_mfma_f32_32x32x16_bf16(av, bA2, acc2, 0, 0, 0);
                av = __builtin_bit_cast(bf16x8, aB);
                acc0 = __builtin_amdgcn_mfma_f32_32x32x16_bf16(av, bB0, acc0, 0, 0, 0);
                acc1 = __builtin_amdgcn_mfma_f32_32x32x16_bf16(av, bB1, acc1, 0, 0, 0);
                acc2 = __builtin_amdgcn_mfma_f32_32x32x16_bf16(av, bB2, acc2, 0, 0, 0);
            }

            __syncthreads();   // all waves done reading Xbuf before overwrite

            // epilogue: silu + JVP coupling; D col = sample = l31,
            // D row n = n0w + (reg&3) + 8*(reg>>2) + 4*hi  (m74 layout, verified)
            {
                char* pb = (char*)Xbuf + (l31 << 10);
                #pragma unroll
                for (int q = 0; q < 4; ++q) {
                    int nq = n0w + 8 * q + 4 * hi;          // 4 consecutive n
                    f32x4 bq = *(const f32x4*)(bias + nq);
                    float hv[4], u0v[4], u1v[4];
                    #pragma unroll
                    for (int k = 0; k < 4; ++k) {
                        int reg = 4 * q + k;
                        float aa  = acc0[reg] + bq[k];
                        float sig = 1.0f / (1.0f + __expf(-aa));
                        float h   = aa * sig;
                        float sp  = fmaf(h, 1.0f - sig, sig);
                        hv[k]  = h;
                        u0v[k] = sp * acc1[reg];
                        u1v[k] = sp * acc2[reg];
                    }
                    int off = (nq << 1) ^ swzB;
                    uint2 vh = {pkbf2(hv[0],  hv[1]),  pkbf2(hv[2],  hv[3])};
                    uint2 v0 = {pkbf2(u0v[0], u0v[1]), pkbf2(u0v[2], u0v[3])};
                    uint2 v1 = {pkbf2(u1v[0], u1v[1]), pkbf2(u1v[2], u1v[3])};
                    *(uint2*)(pb + off)              = vh;
                    *(uint2*)(pb + (32 << 10) + off) = v0;
                    *(uint2*)(pb + (64 << 10) + off) = v1;
                }
            }
            __syncthreads();
        }

        // ---------- layer 3: six length-512 dots, two 8-elem passes ----------
        {
            float d0 = 0.f, d1 = 0.f, d2 = 0.f, d3 = 0.f, d4 = 0.f, d5 = 0.f;
            #pragma unroll
            for (int p = 0; p < 2; ++p) {
                int eb = (t32 << 4) + (p << 3);    // element base, 8 elems
                const float4* wr0 = (const float4*)(W3 + eb);
                const float4* wr1 = (const float4*)(W3 + 512 + eb);
                float4 wa0 = wr0[0], wa1 = wr0[1];
                float4 wb0 = wr1[0], wb1 = wr1[1];
                #pragma unroll
                for (int st = 0; st < 3; ++st) {
                    int row = s0 + st * 32;
                    int off = (row << 10) + ((((t32 << 5) + (p << 4))) ^ swz0);
                    uint4 v = *(const uint4*)((const char*)Xbuf + off);
                    float e0 = __uint_as_float(v.x << 16);
                    float e1 = __uint_as_float(v.x & 0xffff0000u);
                    float e2 = __uint_as_float(v.y << 16);
                    float e3 = __uint_as_float(v.y & 0xffff0000u);
                    float e4 = __uint_as_float(v.z << 16);
                    float e5 = __uint_as_float(v.z & 0xffff0000u);
                    float e6 = __uint_as_float(v.w << 16);
                    float e7 = __uint_as_float(v.w & 0xffff0000u);
                    float sa = wa0.x * e0;
                    sa = fmaf(wa0.y, e1, sa); sa = fmaf(wa0.z, e2, sa);
                    sa = fmaf(wa0.w, e3, sa); sa = fmaf(wa1.x, e4, sa);
                    sa = fmaf(wa1.y, e5, sa); sa = fmaf(wa1.z, e6, sa);
                    sa = fmaf(wa1.w, e7, sa);
                    float sb = wb0.x * e0;
                    sb = fmaf(wb0.y, e1, sb); sb = fmaf(wb0.z, e2, sb);
                    sb = fmaf(wb0.w, e3, sb); sb = fmaf(wb1.x, e4, sb);
                    sb = fmaf(wb1.y, e5, sb); sb = fmaf(wb1.z, e6, sb);
                    sb = fmaf(wb1.w, e7, sb);
                    if      (st == 0) { d0 += sa; d1 += sb; }
                    else if (st == 1) { d2 += sa; d3 += sb; }
                    else              { d4 += sa; d5 += sb; }
                }
            }
            #pragma unroll
            for (int m = 1; m < 32; m <<= 1) {
                d0 += __shfl_xor(d0, m);
                d1 += __shfl_xor(d1, m);
                d2 += __shfl_xor(d2, m);
                d3 += __shfl_xor(d3, m);
                d4 += __shfl_xor(d4, m);
                d5 += __shfl_xor(d5, m);
            }
            if (t32 == 0) {
                float v0 = d0 + b3v[0];
                float v1 = d1 + b3v[1];
                float det = (1.0f + 0.1f * d2) * (1.0f + 0.1f * d5)
                          - 0.01f * d4 * d3;
                ldbuf[s0] += logf(fmaxf(fabsf(det), 1e-8f));
                zbuf[s0][0] += 0.1f * v0;
                zbuf[s0][1] += 0.1f * v1;
            }
        }
        __syncthreads();
    }

    if (tid < 32) {
        float z0 = zbuf[tid][0], z1 = zbuf[tid][1];
        out[wgs + tid] = -0.5f * (z0 * z0 + z1 * z1) - 1.8378770664093453f + ldbuf[tid];
    }
}

extern "C" void kernel_launch(void* const* d_in, const int* in_sizes, int n_in,
                              void* d_out, int out_size, void* d_ws, size_t ws_size,
                              hipStream_t stream) {
    const float* x  = (const float*)d_in[0];
    const float* W0 = (const float*)d_in[1];   // (512, 34)
    const float* b0 = (const float*)d_in[2];
    const float* W1 = (const float*)d_in[3];   // (512, 512)
    const float* b1 = (const float*)d_in[4];
    const float* W2 = (const float*)d_in[5];
    const float* b2 = (const float*)d_in[6];
    const float* W3 = (const float*)d_in[7];   // (2, 512)
    const float* b3 = (const float*)d_in[8];
    float* out = (float*)d_out;

    char* ws = (char*)d_ws;
    __hip_bfloat16* wpk1 = (__hip_bfloat16*)ws;                  // 512 KB
    __hip_bfloat16* wpk2 = (__hip_bfloat16*)(ws + (512u << 10)); // 512 KB
    float*          cstp = (float*)(ws + (1024u << 10));         // 20 KB
    float*          w01p = (float*)(ws + (1044u << 10));         // 4 KB

    pack_w_kernel<<<512, 512, 0, stream>>>(W1, wpk1);
    pack_w_kernel<<<512, 512, 0, stream>>>(W2, wpk2);
    cstep_kernel<<<10, 512, 0, stream>>>(W0, b0, cstp);
    pack_w0_kernel<<<1, 512, 0, stream>>>(W0, w01p);
    flow_kernel<<<131072 / 32, 1024, 0, stream>>>(x, w01p, cstp, wpk1, wpk2,
                                                  b1, b2, W3, b3, out);
}

// Round 15
// 5707.151 us; speedup vs baseline: 1.3250x; 1.1812x over previous
//
#include <hip/hip_runtime.h>
#include <hip/hip_bf16.h>
#include <math.h>

// DiffusionFlow: fused 10-step flow + log-det on MI355X.
// Round 15 = r14 geometry (32 samples/WG, 1024 thr / 16 waves, wave owns 32
// cols, 32x32x16 intrinsic MFMA, acc in AGPR) with REGISTER-MINIMAL phases:
//  - K-loop: wrap-around depth-1 A prefetch ((c+1)&31, guard-free), B frags
//    just-in-time, unroll 2. TLP (4 waves/SIMD) is the latency hider; the
//    manual double-buffers of r10-r14 were what overflowed the 64-arch budget
//    (1.3-2.1 GB spills, 4 rounds running).
//  - L0 m-loop and L3 p-loop ROLLED (unroll 1): one 8-out block live at a time.
// Xbuf rows: h 0-31, u0 32-63, u1 64-95; swizzle byteoff ^= (row&7)<<4.

typedef float  f32x4  __attribute__((ext_vector_type(4)));
typedef float  f32x16 __attribute__((ext_vector_type(16)));
typedef __bf16 bf16x8 __attribute__((ext_vector_type(8)));

static __device__ __forceinline__ unsigned pkbf2(float a, float b) {
    unsigned short lo = __builtin_bit_cast(unsigned short, __float2bfloat16(a));
    unsigned short hi = __builtin_bit_cast(unsigned short, __float2bfloat16(b));
    return (unsigned)lo | ((unsigned)hi << 16);
}

// ---- pack W (512x512 row-major fp32) -> bf16 A-frag order for 32x32x16 ----
// out[(((c*16+nb)*64)+l)*8+j] = W[nb*32+(l&31)][c*16+(l>>5)*8+j]  (verified r5-r14)
__global__ void pack_w_kernel(const float* __restrict__ W,
                              __hip_bfloat16* __restrict__ out) {
    int i  = blockIdx.x * 512 + threadIdx.x;
    int c  = i >> 13;
    int nb = (i >> 9) & 15;
    int l  = (i >> 3) & 63;
    int j  = i & 7;
    int n  = nb * 32 + (l & 31);
    int k  = c * 16 + ((l >> 5) << 3) + j;
    out[i] = __float2bfloat16(W[n * 512 + k]);
}

// ---- pack W0 cols 0,1 -> contiguous [512][2] fp32 ----
__global__ void pack_w0_kernel(const float* __restrict__ W0,
                               float* __restrict__ w01) {
    int o = threadIdx.x;
    w01[o * 2 + 0] = W0[o * 34 + 0];
    w01[o * 2 + 1] = W0[o * 34 + 1];
}

// ---- c_step[k][o] = b0[o] + W0[o,2:34] . temb(t_k) ----
__global__ void cstep_kernel(const float* __restrict__ W0,
                             const float* __restrict__ b0,
                             float* __restrict__ cst) {
    int k = blockIdx.x;
    int o = threadIdx.x;
    float t = (float)k * 0.1f;
    float acc = b0[o];
    #pragma unroll
    for (int j = 0; j < 16; ++j) {
        float f   = expf(-9.210340371976184f * (float)j / 16.0f);
        float arg = t * f;
        acc += W0[o * 34 + 2 + j]  * sinf(arg);
        acc += W0[o * 34 + 18 + j] * cosf(arg);
    }
    cst[k * 512 + o] = acc;
}

__global__ __launch_bounds__(1024)
void flow_kernel(const float* __restrict__ x,
                 const float* __restrict__ w01,
                 const float* __restrict__ cst,
                 const __hip_bfloat16* __restrict__ Wpk1,
                 const __hip_bfloat16* __restrict__ Wpk2,
                 const float* __restrict__ b1,
                 const float* __restrict__ b2,
                 const float* __restrict__ W3,
                 const float* __restrict__ b3v,
                 float* __restrict__ out)
{
    __shared__ __align__(16) __hip_bfloat16 Xbuf[96 * 512];  // 96 KB
    __shared__ float zbuf[32][2];
    __shared__ float ldbuf[32];

    const int tid  = threadIdx.x;
    const int lane = tid & 63;
    const int wid  = tid >> 6;        // 0..15 -> cols [wid*32, wid*32+32)
    const int l31  = lane & 31;
    const int hi   = lane >> 5;       // 0/1
    const int n0w  = wid << 5;
    const int wgs  = blockIdx.x << 5; // 32 samples per WG

    if (tid < 32) {
        zbuf[tid][0] = x[(wgs + tid) * 2 + 0];
        zbuf[tid][1] = x[(wgs + tid) * 2 + 1];
        ldbuf[tid]   = 0.0f;
    }

    // B-frag (X from LDS): rows l31 / 32+l31 / 64+l31
    const int rowb0 = l31 << 10;
    const int rowb1 = (32 + l31) << 10;
    const int rowb2 = (64 + l31) << 10;
    const int swzB  = (l31 & 7) << 4;
    const int hi16  = hi << 4;
    // A-frag: uint4 index = c*1024 + abase  (wave wid owns n-block wid)
    const int abase = (wid << 6) + lane;
    const uint4* Wp1 = (const uint4*)Wpk1;
    const uint4* Wp2 = (const uint4*)Wpk2;

    // L0/L3 split: s0 = sample (tid>>5, 0..31), t32 = 32-way column split
    const int s0   = tid >> 5;
    const int t32  = tid & 31;
    const int swz0 = (s0 & 7) << 4;

    const char* xb = (const char*)Xbuf;

    __syncthreads();

    #pragma unroll 1
    for (int step = 0; step < 10; ++step) {
        // ---------- layer 0: rank-2 + step-constant, 16 outs/thread ----------
        {
            const float z0 = zbuf[s0][0];
            const float z1 = zbuf[s0][1];
            const float* cs = cst + (step << 9);
            char* base0 = (char*)Xbuf + (s0 << 10);
            #pragma unroll 1
            for (int m = 0; m < 2; ++m) {
                int ob = (t32 << 4) + (m << 3);    // element base, 8 outs
                const float4* wv4 = (const float4*)(w01 + (ob << 1));
                const float4* cv4 = (const float4*)(cs + ob);
                unsigned ph[4], p0[4], p1[4];
                #pragma unroll
                for (int jj = 0; jj < 4; ++jj) {
                    float4 wv = wv4[jj];                    // pairs (x,y),(z,w)
                    float4 cv = cv4[jj >> 1];
                    float c0 = (jj & 1) ? cv.z : cv.x;
                    float c1 = (jj & 1) ? cv.w : cv.y;
                    float a0  = fmaf(z0, wv.x, fmaf(z1, wv.y, c0));
                    float sg0 = 1.0f / (1.0f + __expf(-a0));
                    float h0  = a0 * sg0;
                    float sp0 = fmaf(h0, 1.0f - sg0, sg0);  // silu'(a0)
                    float a1  = fmaf(z0, wv.z, fmaf(z1, wv.w, c1));
                    float sg1 = 1.0f / (1.0f + __expf(-a1));
                    float h1  = a1 * sg1;
                    float sp1 = fmaf(h1, 1.0f - sg1, sg1);
                    ph[jj] = pkbf2(h0, h1);
                    p0[jj] = pkbf2(sp0 * wv.x, sp1 * wv.z);
                    p1[jj] = pkbf2(sp0 * wv.y, sp1 * wv.w);
                }
                int off = (ob << 1) ^ swz0;
                uint4 vph = {ph[0], ph[1], ph[2], ph[3]};
                uint4 vp0 = {p0[0], p0[1], p0[2], p0[3]};
                uint4 vp1 = {p1[0], p1[1], p1[2], p1[3]};
                *(uint4*)(base0 + off)              = vph;
                *(uint4*)(base0 + (32 << 10) + off) = vp0;
                *(uint4*)(base0 + (64 << 10) + off) = vp1;
            }
        }
        __syncthreads();

        // ---------- layers 1,2: D = W @ X^T via 32x32x16 MFMA (intrinsic) ----------
        #pragma unroll 1
        for (int layer = 0; layer < 2; ++layer) {
            const uint4* __restrict__ Wp   = layer ? Wp2 : Wp1;
            const float* __restrict__ bias = layer ? b2  : b1;

            f32x16 acc0 = (f32x16)(0.0f);   // h stream  (AGPR)
            f32x16 acc1 = (f32x16)(0.0f);   // u0
            f32x16 acc2 = (f32x16)(0.0f);   // u1

            // minimal-live K-loop: wrap-around depth-1 A prefetch, B just-in-time.
            uint4 aCur = Wp[abase];
            #pragma unroll 2
            for (int c = 0; c < 32; ++c) {
                uint4 aNxt = Wp[abase + (((c + 1) & 31) << 10)];
                int kx = ((c << 5) | hi16) ^ swzB;
                bf16x8 bf0 = __builtin_bit_cast(bf16x8, *(const uint4*)(xb + rowb0 + kx));
                bf16x8 bf1 = __builtin_bit_cast(bf16x8, *(const uint4*)(xb + rowb1 + kx));
                bf16x8 bf2 = __builtin_bit_cast(bf16x8, *(const uint4*)(xb + rowb2 + kx));
                bf16x8 av  = __builtin_bit_cast(bf16x8, aCur);
                __builtin_amdgcn_s_setprio(1);
                acc0 = __builtin_amdgcn_mfma_f32_32x32x16_bf16(av, bf0, acc0, 0, 0, 0);
                acc1 = __builtin_amdgcn_mfma_f32_32x32x16_bf16(av, bf1, acc1, 0, 0, 0);
                acc2 = __builtin_amdgcn_mfma_f32_32x32x16_bf16(av, bf2, acc2, 0, 0, 0);
                __builtin_amdgcn_s_setprio(0);
                aCur = aNxt;
            }

            __syncthreads();   // all waves done reading Xbuf before overwrite

            // epilogue: silu + JVP coupling; D col = sample = l31,
            // D row n = n0w + (reg&3) + 8*(reg>>2) + 4*hi  (m74 layout, verified)
            {
                char* pb = (char*)Xbuf + (l31 << 10);
                #pragma unroll
                for (int q = 0; q < 4; ++q) {
                    int nq = n0w + 8 * q + 4 * hi;          // 4 consecutive n
                    f32x4 bq = *(const f32x4*)(bias + nq);
                    float hv[4], u0v[4], u1v[4];
                    #pragma unroll
                    for (int k = 0; k < 4; ++k) {
                        int reg = 4 * q + k;
                        float aa  = acc0[reg] + bq[k];
                        float sig = 1.0f / (1.0f + __expf(-aa));
                        float h   = aa * sig;
                        float sp  = fmaf(h, 1.0f - sig, sig);
                        hv[k]  = h;
                        u0v[k] = sp * acc1[reg];
                        u1v[k] = sp * acc2[reg];
                    }
                    int off = (nq << 1) ^ swzB;
                    uint2 vh = {pkbf2(hv[0],  hv[1]),  pkbf2(hv[2],  hv[3])};
                    uint2 v0 = {pkbf2(u0v[0], u0v[1]), pkbf2(u0v[2], u0v[3])};
                    uint2 v1 = {pkbf2(u1v[0], u1v[1]), pkbf2(u1v[2], u1v[3])};
                    *(uint2*)(pb + off)              = vh;
                    *(uint2*)(pb + (32 << 10) + off) = v0;
                    *(uint2*)(pb + (64 << 10) + off) = v1;
                }
            }
            __syncthreads();
        }

        // ---------- layer 3: six length-512 dots, two rolled 8-elem passes ----------
        {
            float d0 = 0.f, d1 = 0.f, d2 = 0.f, d3 = 0.f, d4 = 0.f, d5 = 0.f;
            #pragma unroll 1
            for (int p = 0; p < 2; ++p) {
                int eb = (t32 << 4) + (p << 3);    // element base, 8 elems
                const float4* wr0 = (const float4*)(W3 + eb);
                const float4* wr1 = (const float4*)(W3 + 512 + eb);
                float4 wa0 = wr0[0], wa1 = wr0[1];
                float4 wb0 = wr1[0], wb1 = wr1[1];
                #pragma unroll
                for (int st = 0; st < 3; ++st) {
                    int row = s0 + st * 32;
                    int off = (row << 10) + ((((t32 << 5) + (p << 4))) ^ swz0);
                    uint4 v = *(const uint4*)((const char*)Xbuf + off);
                    float e0 = __uint_as_float(v.x << 16);
                    float e1 = __uint_as_float(v.x & 0xffff0000u);
                    float e2 = __uint_as_float(v.y << 16);
                    float e3 = __uint_as_float(v.y & 0xffff0000u);
                    float e4 = __uint_as_float(v.z << 16);
                    float e5 = __uint_as_float(v.z & 0xffff0000u);
                    float e6 = __uint_as_float(v.w << 16);
                    float e7 = __uint_as_float(v.w & 0xffff0000u);
                    float sa = wa0.x * e0;
                    sa = fmaf(wa0.y, e1, sa); sa = fmaf(wa0.z, e2, sa);
                    sa = fmaf(wa0.w, e3, sa); sa = fmaf(wa1.x, e4, sa);
                    sa = fmaf(wa1.y, e5, sa); sa = fmaf(wa1.z, e6, sa);
                    sa = fmaf(wa1.w, e7, sa);
                    float sb = wb0.x * e0;
                    sb = fmaf(wb0.y, e1, sb); sb = fmaf(wb0.z, e2, sb);
                    sb = fmaf(wb0.w, e3, sb); sb = fmaf(wb1.x, e4, sb);
                    sb = fmaf(wb1.y, e5, sb); sb = fmaf(wb1.z, e6, sb);
                    sb = fmaf(wb1.w, e7, sb);
                    if      (st == 0) { d0 += sa; d1 += sb; }
                    else if (st == 1) { d2 += sa; d3 += sb; }
                    else              { d4 += sa; d5 += sb; }
                }
            }
            #pragma unroll
            for (int m = 1; m < 32; m <<= 1) {
                d0 += __shfl_xor(d0, m);
                d1 += __shfl_xor(d1, m);
                d2 += __shfl_xor(d2, m);
                d3 += __shfl_xor(d3, m);
                d4 += __shfl_xor(d4, m);
                d5 += __shfl_xor(d5, m);
            }
            if (t32 == 0) {
                float v0 = d0 + b3v[0];
                float v1 = d1 + b3v[1];
                float det = (1.0f + 0.1f * d2) * (1.0f + 0.1f * d5)
                          - 0.01f * d4 * d3;
                ldbuf[s0] += logf(fmaxf(fabsf(det), 1e-8f));
                zbuf[s0][0] += 0.1f * v0;
                zbuf[s0][1] += 0.1f * v1;
            }
        }
        __syncthreads();
    }

    if (tid < 32) {
        float z0 = zbuf[tid][0], z1 = zbuf[tid][1];
        out[wgs + tid] = -0.5f * (z0 * z0 + z1 * z1) - 1.8378770664093453f + ldbuf[tid];
    }
}

extern "C" void kernel_launch(void* const* d_in, const int* in_sizes, int n_in,
                              void* d_out, int out_size, void* d_ws, size_t ws_size,
                              hipStream_t stream) {
    const float* x  = (const float*)d_in[0];
    const float* W0 = (const float*)d_in[1];   // (512, 34)
    const float* b0 = (const float*)d_in[2];
    const float* W1 = (const float*)d_in[3];   // (512, 512)
    const float* b1 = (const float*)d_in[4];
    const float* W2 = (const float*)d_in[5];
    const float* b2 = (const float*)d_in[6];
    const float* W3 = (const float*)d_in[7];   // (2, 512)
    const float* b3 = (const float*)d_in[8];
    float* out = (float*)d_out;

    char* ws = (char*)d_ws;
    __hip_bfloat16* wpk1 = (__hip_bfloat16*)ws;                  // 512 KB
    __hip_bfloat16* wpk2 = (__hip_bfloat16*)(ws + (512u << 10)); // 512 KB
    float*          cstp = (float*)(ws + (1024u << 10));         // 20 KB
    float*          w01p = (float*)(ws + (1044u << 10));         // 4 KB

    pack_w_kernel<<<512, 512, 0, stream>>>(W1, wpk1);
    pack_w_kernel<<<512, 512, 0, stream>>>(W2, wpk2);
    cstep_kernel<<<10, 512, 0, stream>>>(W0, b0, cstp);
    pack_w0_kernel<<<1, 512, 0, stream>>>(W0, w01p);
    flow_kernel<<<131072 / 32, 1024, 0, stream>>>(x, w01p, cstp, wpk1, wpk2,
                                                  b1, b2, W3, b3, out);
}